// Round 2
// baseline (270.388 us; speedup 1.0000x reference)
//
#include <hip/hip_runtime.h>
#include <hip/hip_bf16.h>

// GraphAttentionLayer = flash attention with adjacency mask.
// B=4, N=4096, D_in=128, H=64 (QK dim), D_out=128 (V dim).
// Precision scheme: scores must be ~f32-accurate (softmax amplifies bf16
// rounding of +-70-magnitude scores past the harness threshold), so the
// Whs/Wht GEMM and QK^T use bf16 hi+lo split with 3-term MFMA. P and V are
// single bf16 (error lands well under the 8-ulp output floor).
#define NTOK 4096
#define BATCH 4
#define DIN 128
#define DHID 64
#define DOUT 128
#define NWRD (NTOK / 32)  // 128 bitmask words per row
#define NEG_BIG -9.0e15f

typedef short short8 __attribute__((ext_vector_type(8)));
typedef float floatx4 __attribute__((ext_vector_type(4)));

// float -> bf16 bits, round-to-nearest-even
static __device__ __forceinline__ unsigned short f2bf(float f) {
    unsigned int u = __builtin_bit_cast(unsigned int, f);
    u = (u + 0x7fffu + ((u >> 16) & 1u)) >> 16;
    return (unsigned short)u;
}
static __device__ __forceinline__ float bf2f(unsigned short s) {
    unsigned int u = ((unsigned int)s) << 16;
    return __builtin_bit_cast(float, u);
}

static __device__ __forceinline__ floatx4 mfma16(short8 a, short8 b, floatx4 c) {
    // v_mfma_f32_16x16x32_bf16: A row = lane&15, k = 8*(lane>>4)+{0..7}
    //                           B col = lane&15, k = 8*(lane>>4)+{0..7}
    //                           D col = lane&15, row = 4*(lane>>4)+reg (m89-verified)
    return __builtin_amdgcn_mfma_f32_16x16x32_bf16(a, b, c, 0, 0, 0);
}

// ---------------------------------------------------------------- pack_adj
// bits[n*NWRD + w], bit j = (adj[n][w*32+j] > 0)
__global__ __launch_bounds__(256) void pack_adj_kernel(const int* __restrict__ adj,
                                                       unsigned int* __restrict__ bits) {
    int w = blockIdx.x * 256 + threadIdx.x;
    const int4* p = reinterpret_cast<const int4*>(adj) + (size_t)w * 8;
    unsigned int m = 0;
#pragma unroll
    for (int i = 0; i < 8; ++i) {
        int4 v = p[i];
        m |= (v.x > 0 ? 1u : 0u) << (4 * i + 0);
        m |= (v.y > 0 ? 1u : 0u) << (4 * i + 1);
        m |= (v.z > 0 ? 1u : 0u) << (4 * i + 2);
        m |= (v.w > 0 ? 1u : 0u) << (4 * i + 3);
    }
    bits[w] = m;
}

// ---------------------------------------------------------------- conv_w
// WT_hi[col][k] (col: 0..63 Ws, 64..127 Wt, 128..255 Wc), WT_lo for col<128.
// B-fragment-friendly: k contiguous per col. 96 KB total, stays L2-hot.
__global__ __launch_bounds__(256) void conv_w_kernel(const float* __restrict__ Ws,
                                                     const float* __restrict__ Wt,
                                                     const float* __restrict__ Wc,
                                                     unsigned short* __restrict__ WT_hi,
                                                     unsigned short* __restrict__ WT_lo) {
    int idx = blockIdx.x * 256 + threadIdx.x;  // 0 .. 32767
    int k = idx >> 8, col = idx & 255;
    float w;
    if (col < 64) w = Ws[k * DHID + col];
    else if (col < 128) w = Wt[k * DHID + (col - 64)];
    else w = Wc[k * DOUT + (col - 128)];
    unsigned short hi = f2bf(w);
    WT_hi[col * DIN + k] = hi;
    if (col < 128) WT_lo[col * DIN + k] = f2bf(w - bf2f(hi));
}

// ---------------------------------------------------------------- prep
// Whs/Wht (cols 0..127): hi/lo 3-term MFMA, outputs split hi/lo bf16.
// Whc (cols 128..255): hi-only, stored transposed WhcT[b][d][n] bf16.
__global__ __launch_bounds__(256) void prep_kernel(const float* __restrict__ h,
                                                   const unsigned short* __restrict__ WT_hi,
                                                   const unsigned short* __restrict__ WT_lo,
                                                   unsigned short* __restrict__ Whs_hi,
                                                   unsigned short* __restrict__ Whs_lo,
                                                   unsigned short* __restrict__ Wht_hi,
                                                   unsigned short* __restrict__ Wht_lo,
                                                   unsigned short* __restrict__ WhcT) {
    int tid = threadIdx.x;
    int b = blockIdx.y;
    int w = tid >> 6, lane = tid & 63, lg = lane >> 4, lc = lane & 15;
    int n0 = blockIdx.x * 64 + w * 16;
    const float* hrow = h + (size_t)(b * NTOK + n0 + lc) * DIN;

    short8 ah[4], al[4];
#pragma unroll
    for (int ks = 0; ks < 4; ++ks) {
        float4 f0 = *reinterpret_cast<const float4*>(hrow + ks * 32 + lg * 8);
        float4 f1 = *reinterpret_cast<const float4*>(hrow + ks * 32 + lg * 8 + 4);
        float x[8] = {f0.x, f0.y, f0.z, f0.w, f1.x, f1.y, f1.z, f1.w};
        short8 hh, ll;
#pragma unroll
        for (int j = 0; j < 8; ++j) {
            unsigned short hb = f2bf(x[j]);
            hh[j] = (short)hb;
            ll[j] = (short)f2bf(x[j] - bf2f(hb));
        }
        ah[ks] = hh;
        al[ks] = ll;
    }

#pragma unroll
    for (int ct = 0; ct < 16; ++ct) {
        floatx4 acc = {0.f, 0.f, 0.f, 0.f};
        const unsigned short* bbase = WT_hi + (size_t)(ct * 16 + lc) * DIN;
        const unsigned short* lbase = WT_lo + (size_t)(ct * 16 + lc) * DIN;
#pragma unroll
        for (int ks = 0; ks < 4; ++ks) {
            short8 bh = *reinterpret_cast<const short8*>(bbase + ks * 32 + lg * 8);
            acc = mfma16(ah[ks], bh, acc);
            if (ct < 8) {  // Ws/Wt cols: add cross terms for f32-level accuracy
                short8 bl = *reinterpret_cast<const short8*>(lbase + ks * 32 + lg * 8);
                acc = mfma16(ah[ks], bl, acc);
                acc = mfma16(al[ks], bh, acc);
            }
        }
        int col = ct * 16 + lc;
        int nr = n0 + 4 * lg;
        if (col < 64) {
#pragma unroll
            for (int r = 0; r < 4; ++r) {
                float v = acc[r];
                unsigned short hb = f2bf(v);
                size_t o = (size_t)(b * NTOK + nr + r) * DHID + col;
                Whs_hi[o] = hb;
                Whs_lo[o] = f2bf(v - bf2f(hb));
            }
        } else if (col < 128) {
#pragma unroll
            for (int r = 0; r < 4; ++r) {
                float v = acc[r];
                unsigned short hb = f2bf(v);
                size_t o = (size_t)(b * NTOK + nr + r) * DHID + (col - 64);
                Wht_hi[o] = hb;
                Wht_lo[o] = f2bf(v - bf2f(hb));
            }
        } else {
            unsigned int p01 = (unsigned int)f2bf(acc[0]) | ((unsigned int)f2bf(acc[1]) << 16);
            unsigned int p23 = (unsigned int)f2bf(acc[2]) | ((unsigned int)f2bf(acc[3]) << 16);
            unsigned int* dst =
                reinterpret_cast<unsigned int*>(&WhcT[(size_t)(b * DOUT + col - 128) * NTOK + nr]);
            dst[0] = p01;
            dst[1] = p23;
        }
    }
}

// ---------------------------------------------------------------- attn
// grid (N/64, B), 256 threads. Wave w owns q-rows q0..q0+15, iterates all keys
// in 64-key tiles staged in LDS. QK^T in hi/lo (6 MFMA / 16x64 subtile).
__global__ __launch_bounds__(256) void attn_kernel(const unsigned short* __restrict__ Whs_hi,
                                                   const unsigned short* __restrict__ Whs_lo,
                                                   const unsigned short* __restrict__ Wht_hi,
                                                   const unsigned short* __restrict__ Wht_lo,
                                                   const unsigned short* __restrict__ WhcT,
                                                   const unsigned int* __restrict__ bits,
                                                   float* __restrict__ out) {
    __shared__ unsigned short Kh_lds[64][72];   // [key][h] hi, pad 72
    __shared__ unsigned short Kl_lds[64][72];   // [key][h] lo
    __shared__ unsigned short V_lds[128][72];   // [d][key]
    __shared__ unsigned short P_lds[4][16][72]; // per wave: [q][key]

    int tid = threadIdx.x;
    int b = blockIdx.y;
    int w = tid >> 6, lane = tid & 63, lg = lane >> 4, lc = lane & 15;
    int q0 = blockIdx.x * 64 + w * 16;

    // Q fragments (hoisted): A row = lc (query), k = h
    {
    }
    const unsigned short* qrowH = Whs_hi + (size_t)(b * NTOK + q0 + lc) * DHID;
    const unsigned short* qrowL = Whs_lo + (size_t)(b * NTOK + q0 + lc) * DHID;
    short8 qh0 = *reinterpret_cast<const short8*>(qrowH + lg * 8);
    short8 qh1 = *reinterpret_cast<const short8*>(qrowH + 32 + lg * 8);
    short8 ql0 = *reinterpret_cast<const short8*>(qrowL + lg * 8);
    short8 ql1 = *reinterpret_cast<const short8*>(qrowL + 32 + lg * 8);

    floatx4 o[8];
#pragma unroll
    for (int dt = 0; dt < 8; ++dt) o[dt] = (floatx4){0.f, 0.f, 0.f, 0.f};
    float m[4], l[4];
#pragma unroll
    for (int r = 0; r < 4; ++r) { m[r] = NEG_BIG; l[r] = 0.f; }

    // staging: K rows are 128B (8 chunks of 16B); thread does 2 chunks hi,
    // 2 chunks lo. V rows are 128B; thread does 4 chunks.
    int kkey = tid >> 2, koff = (tid & 3) * 16;
    int vd = tid >> 1, voff = (tid & 1) * 32;

    for (int it = 0; it < NTOK / 64; ++it) {
        int kb = it * 64;
        const unsigned short* ksrcH = Wht_hi + (size_t)(b * NTOK + kb + kkey) * DHID + koff;
        const unsigned short* ksrcL = Wht_lo + (size_t)(b * NTOK + kb + kkey) * DHID + koff;
        short8 krH0 = *reinterpret_cast<const short8*>(ksrcH);
        short8 krH1 = *reinterpret_cast<const short8*>(ksrcH + 8);
        short8 krL0 = *reinterpret_cast<const short8*>(ksrcL);
        short8 krL1 = *reinterpret_cast<const short8*>(ksrcL + 8);
        const unsigned short* vsrc = WhcT + (size_t)(b * DOUT + vd) * NTOK + kb + voff;
        short8 vr0 = *reinterpret_cast<const short8*>(vsrc);
        short8 vr1 = *reinterpret_cast<const short8*>(vsrc + 8);
        short8 vr2 = *reinterpret_cast<const short8*>(vsrc + 16);
        short8 vr3 = *reinterpret_cast<const short8*>(vsrc + 24);
        __syncthreads();  // previous tile's compute done
        *reinterpret_cast<short8*>(&Kh_lds[kkey][koff]) = krH0;
        *reinterpret_cast<short8*>(&Kh_lds[kkey][koff + 8]) = krH1;
        *reinterpret_cast<short8*>(&Kl_lds[kkey][koff]) = krL0;
        *reinterpret_cast<short8*>(&Kl_lds[kkey][koff + 8]) = krL1;
        *reinterpret_cast<short8*>(&V_lds[vd][voff]) = vr0;
        *reinterpret_cast<short8*>(&V_lds[vd][voff + 8]) = vr1;
        *reinterpret_cast<short8*>(&V_lds[vd][voff + 16]) = vr2;
        *reinterpret_cast<short8*>(&V_lds[vd][voff + 24]) = vr3;
        __syncthreads();  // tile visible

        // S = Q K^T with hi/lo cross terms. D col = lc = key, row = 4*lg+r = q
        floatx4 s[4];
#pragma unroll
        for (int kc = 0; kc < 4; ++kc) {
            short8 kh0 = *reinterpret_cast<const short8*>(&Kh_lds[kc * 16 + lc][lg * 8]);
            short8 kh1 = *reinterpret_cast<const short8*>(&Kh_lds[kc * 16 + lc][32 + lg * 8]);
            short8 kl0 = *reinterpret_cast<const short8*>(&Kl_lds[kc * 16 + lc][lg * 8]);
            short8 kl1 = *reinterpret_cast<const short8*>(&Kl_lds[kc * 16 + lc][32 + lg * 8]);
            floatx4 acc = {0.f, 0.f, 0.f, 0.f};
            acc = mfma16(qh0, kh0, acc);
            acc = mfma16(qh1, kh1, acc);
            acc = mfma16(ql0, kh0, acc);
            acc = mfma16(ql1, kh1, acc);
            acc = mfma16(qh0, kl0, acc);
            acc = mfma16(qh1, kl1, acc);
            s[kc] = acc;
        }

        // adjacency mask
#pragma unroll
        for (int r = 0; r < 4; ++r) {
            int n = q0 + 4 * lg + r;
            unsigned int w0 = bits[n * NWRD + (kb >> 5)];
            unsigned int w1 = bits[n * NWRD + (kb >> 5) + 1];
#pragma unroll
            for (int kc = 0; kc < 4; ++kc) {
                unsigned int word = (kc & 2) ? w1 : w0;
                int bit = ((kc & 1) * 16) + lc;
                if (!((word >> bit) & 1u)) s[kc][r] = NEG_BIG;
            }
        }

        // online softmax (row owned per lg-group; reduce across 16 key-lanes)
        float mn[4], sc[4], rs[4];
#pragma unroll
        for (int r = 0; r < 4; ++r) {
            float vm = fmaxf(fmaxf(s[0][r], s[1][r]), fmaxf(s[2][r], s[3][r]));
            vm = fmaxf(vm, __shfl_xor(vm, 1));
            vm = fmaxf(vm, __shfl_xor(vm, 2));
            vm = fmaxf(vm, __shfl_xor(vm, 4));
            vm = fmaxf(vm, __shfl_xor(vm, 8));
            float mnr = fmaxf(m[r], vm);
            sc[r] = __expf(m[r] - mnr);
            mn[r] = mnr;
            m[r] = mnr;
            rs[r] = 0.f;
        }
#pragma unroll
        for (int kc = 0; kc < 4; ++kc)
#pragma unroll
            for (int r = 0; r < 4; ++r) {
                float p = __expf(s[kc][r] - mn[r]);
                s[kc][r] = p;
                rs[r] += p;
            }
#pragma unroll
        for (int r = 0; r < 4; ++r) {
            float t = rs[r];
            t += __shfl_xor(t, 1);
            t += __shfl_xor(t, 2);
            t += __shfl_xor(t, 4);
            t += __shfl_xor(t, 8);
            l[r] = l[r] * sc[r] + t;
        }
#pragma unroll
        for (int dt = 0; dt < 8; ++dt)
#pragma unroll
            for (int r = 0; r < 4; ++r) o[dt][r] *= sc[r];

        // P (bf16) -> LDS roundtrip to get PV A-operand layout (row=q, k=key)
#pragma unroll
        for (int kc = 0; kc < 4; ++kc)
#pragma unroll
            for (int r = 0; r < 4; ++r)
                P_lds[w][4 * lg + r][kc * 16 + lc] = f2bf(s[kc][r]);
        asm volatile("s_waitcnt lgkmcnt(0)" ::: "memory");
        __builtin_amdgcn_sched_barrier(0);
        short8 pa0 = *reinterpret_cast<const short8*>(&P_lds[w][lc][lg * 8]);
        short8 pa1 = *reinterpret_cast<const short8*>(&P_lds[w][lc][32 + lg * 8]);

        // O += P V  (V_lds[d][key]: B col = lc = d, k = contiguous keys)
#pragma unroll
        for (int dt = 0; dt < 8; ++dt) {
            short8 vf0 = *reinterpret_cast<const short8*>(&V_lds[dt * 16 + lc][lg * 8]);
            o[dt] = mfma16(pa0, vf0, o[dt]);
        }
#pragma unroll
        for (int dt = 0; dt < 8; ++dt) {
            short8 vf1 = *reinterpret_cast<const short8*>(&V_lds[dt * 16 + lc][32 + lg * 8]);
            o[dt] = mfma16(pa1, vf1, o[dt]);
        }
    }

    // epilogue: normalize and store (f32)
#pragma unroll
    for (int r = 0; r < 4; ++r) {
        float inv = 1.0f / l[r];
        float* orow = out + (size_t)(b * NTOK + q0 + 4 * lg + r) * DOUT;
#pragma unroll
        for (int dt = 0; dt < 8; ++dt) orow[dt * 16 + lc] = o[dt][r] * inv;
    }
}

// ---------------------------------------------------------------- launch
extern "C" void kernel_launch(void* const* d_in, const int* in_sizes, int n_in,
                              void* d_out, int out_size, void* d_ws, size_t ws_size,
                              hipStream_t stream) {
    const float* h   = (const float*)d_in[0];
    const int*   adj = (const int*)d_in[1];
    const float* Ws  = (const float*)d_in[2];
    const float* Wt  = (const float*)d_in[3];
    const float* Wc  = (const float*)d_in[4];
    float* out = (float*)d_out;

    // workspace layout (~14.2 MiB)
    size_t nq = (size_t)BATCH * NTOK * DHID;           // 1 Mi elements
    unsigned short* Whs_hi = (unsigned short*)d_ws;    // 2 MiB
    unsigned short* Whs_lo = Whs_hi + nq;              // 2 MiB
    unsigned short* Wht_hi = Whs_lo + nq;              // 2 MiB
    unsigned short* Wht_lo = Wht_hi + nq;              // 2 MiB
    unsigned short* WhcT   = Wht_lo + nq;              // 4 MiB
    unsigned int*   bits   = (unsigned int*)(WhcT + (size_t)BATCH * DOUT * NTOK);  // 2 MiB
    unsigned short* WT_hi  = (unsigned short*)(bits + (size_t)NTOK * NWRD);        // 64 KiB
    unsigned short* WT_lo  = WT_hi + 256 * DIN;                                    // 32 KiB

    pack_adj_kernel<<<dim3(NTOK * NWRD / 256), dim3(256), 0, stream>>>(adj, bits);
    conv_w_kernel<<<dim3(128), dim3(256), 0, stream>>>(Ws, Wt, Wc, WT_hi, WT_lo);
    prep_kernel<<<dim3(NTOK / 64, BATCH), dim3(256), 0, stream>>>(
        h, WT_hi, WT_lo, Whs_hi, Whs_lo, Wht_hi, Wht_lo, WhcT);
    attn_kernel<<<dim3(NTOK / 64, BATCH), dim3(256), 0, stream>>>(
        Whs_hi, Whs_lo, Wht_hi, Wht_lo, WhcT, bits, out);
}

// Round 3
// 230.204 us; speedup vs baseline: 1.1746x; 1.1746x over previous
//
#include <hip/hip_runtime.h>
#include <hip/hip_bf16.h>

// GraphAttentionLayer = flash attention with adjacency mask.
// B=4, N=4096, D_in=128, H=64 (QK dim), D_out=128 (V dim).
// Precision: scores need ~f32 accuracy (softmax amplifies bf16 rounding of
// +-70-magnitude scores) -> Whs/Wht GEMM and QK^T use bf16 hi+lo 3-term MFMA.
// P, V, partial-O are single bf16 (lands well under the 8-ulp output floor).
// Parallelism: split-K over keys (SPLIT=4) -> 1024 attn blocks (3/CU, LDS-capped)
// + T14 reg-staged prefetch to hide global latency inside each wave.
#define NTOK 4096
#define BATCH 4
#define DIN 128
#define DHID 64
#define DOUT 128
#define NWRD (NTOK / 32)
#define SPLIT 4
#define ITERS (NTOK / SPLIT / 64)  // 16 key-tiles per split
#define NEG_BIG -9.0e15f

typedef short short8 __attribute__((ext_vector_type(8)));
typedef float floatx4 __attribute__((ext_vector_type(4)));

static __device__ __forceinline__ unsigned short f2bf(float f) {
    unsigned int u = __builtin_bit_cast(unsigned int, f);
    u = (u + 0x7fffu + ((u >> 16) & 1u)) >> 16;
    return (unsigned short)u;
}
static __device__ __forceinline__ float bf2f(unsigned short s) {
    unsigned int u = ((unsigned int)s) << 16;
    return __builtin_bit_cast(float, u);
}

static __device__ __forceinline__ floatx4 mfma16(short8 a, short8 b, floatx4 c) {
    // v_mfma_f32_16x16x32_bf16: A row = lane&15, k = 8*(lane>>4)+{0..7}
    //                           B col = lane&15, k = 8*(lane>>4)+{0..7}
    //                           D col = lane&15, row = 4*(lane>>4)+reg
    return __builtin_amdgcn_mfma_f32_16x16x32_bf16(a, b, c, 0, 0, 0);
}

// ---------------------------------------------------------------- pack_adj
__global__ __launch_bounds__(256) void pack_adj_kernel(const int* __restrict__ adj,
                                                       unsigned int* __restrict__ bits) {
    int w = blockIdx.x * 256 + threadIdx.x;
    const int4* p = reinterpret_cast<const int4*>(adj) + (size_t)w * 8;
    unsigned int m = 0;
#pragma unroll
    for (int i = 0; i < 8; ++i) {
        int4 v = p[i];
        m |= (v.x > 0 ? 1u : 0u) << (4 * i + 0);
        m |= (v.y > 0 ? 1u : 0u) << (4 * i + 1);
        m |= (v.z > 0 ? 1u : 0u) << (4 * i + 2);
        m |= (v.w > 0 ? 1u : 0u) << (4 * i + 3);
    }
    bits[w] = m;
}

// ---------------------------------------------------------------- conv_w
// WT_hi[col][k] (col: 0..63 Ws, 64..127 Wt, 128..255 Wc), WT_lo for col<128.
__global__ __launch_bounds__(256) void conv_w_kernel(const float* __restrict__ Ws,
                                                     const float* __restrict__ Wt,
                                                     const float* __restrict__ Wc,
                                                     unsigned short* __restrict__ WT_hi,
                                                     unsigned short* __restrict__ WT_lo) {
    int idx = blockIdx.x * 256 + threadIdx.x;
    int k = idx >> 8, col = idx & 255;
    float w;
    if (col < 64) w = Ws[k * DHID + col];
    else if (col < 128) w = Wt[k * DHID + (col - 64)];
    else w = Wc[k * DOUT + (col - 128)];
    unsigned short hi = f2bf(w);
    WT_hi[col * DIN + k] = hi;
    if (col < 128) WT_lo[col * DIN + k] = f2bf(w - bf2f(hi));
}

// ---------------------------------------------------------------- prep
// grid (N/16, B), 256 thr. All 4 waves share 16 rows; wave w owns 64 cols:
// w0 -> Whs (3-term), w1 -> Wht (3-term), w2/w3 -> Whc (hi only, transposed).
__global__ __launch_bounds__(256) void prep_kernel(const float* __restrict__ h,
                                                   const unsigned short* __restrict__ WT_hi,
                                                   const unsigned short* __restrict__ WT_lo,
                                                   unsigned short* __restrict__ Whs_hi,
                                                   unsigned short* __restrict__ Whs_lo,
                                                   unsigned short* __restrict__ Wht_hi,
                                                   unsigned short* __restrict__ Wht_lo,
                                                   unsigned short* __restrict__ WhcT) {
    int tid = threadIdx.x;
    int b = blockIdx.y;
    int w = tid >> 6, lane = tid & 63, lg = lane >> 4, lc = lane & 15;
    int n0 = blockIdx.x * 16;
    const float* hrow = h + (size_t)(b * NTOK + n0 + lc) * DIN;

    short8 ah[4], al[4];
#pragma unroll
    for (int ks = 0; ks < 4; ++ks) {
        float4 f0 = *reinterpret_cast<const float4*>(hrow + ks * 32 + lg * 8);
        float4 f1 = *reinterpret_cast<const float4*>(hrow + ks * 32 + lg * 8 + 4);
        float x[8] = {f0.x, f0.y, f0.z, f0.w, f1.x, f1.y, f1.z, f1.w};
        short8 hh, ll;
#pragma unroll
        for (int j = 0; j < 8; ++j) {
            unsigned short hb = f2bf(x[j]);
            hh[j] = (short)hb;
            ll[j] = (short)f2bf(x[j] - bf2f(hb));
        }
        ah[ks] = hh;
        al[ks] = ll;
    }

#pragma unroll
    for (int ci = 0; ci < 4; ++ci) {
        int ct = w * 4 + ci;
        int col = ct * 16 + lc;
        const unsigned short* bbase = WT_hi + (size_t)col * DIN;
        const unsigned short* lbase = WT_lo + (size_t)col * DIN;
        floatx4 acc = {0.f, 0.f, 0.f, 0.f};
#pragma unroll
        for (int ks = 0; ks < 4; ++ks) {
            short8 bh = *reinterpret_cast<const short8*>(bbase + ks * 32 + lg * 8);
            acc = mfma16(ah[ks], bh, acc);
            if (w < 2) {
                short8 bl = *reinterpret_cast<const short8*>(lbase + ks * 32 + lg * 8);
                acc = mfma16(ah[ks], bl, acc);
                acc = mfma16(al[ks], bh, acc);
            }
        }
        int nr = n0 + 4 * lg;
        if (w == 0) {
#pragma unroll
            for (int r = 0; r < 4; ++r) {
                float v = acc[r];
                unsigned short hb = f2bf(v);
                size_t o = (size_t)(b * NTOK + nr + r) * DHID + col;
                Whs_hi[o] = hb;
                Whs_lo[o] = f2bf(v - bf2f(hb));
            }
        } else if (w == 1) {
#pragma unroll
            for (int r = 0; r < 4; ++r) {
                float v = acc[r];
                unsigned short hb = f2bf(v);
                size_t o = (size_t)(b * NTOK + nr + r) * DHID + (col - 64);
                Wht_hi[o] = hb;
                Wht_lo[o] = f2bf(v - bf2f(hb));
            }
        } else {
            unsigned int p01 = (unsigned int)f2bf(acc[0]) | ((unsigned int)f2bf(acc[1]) << 16);
            unsigned int p23 = (unsigned int)f2bf(acc[2]) | ((unsigned int)f2bf(acc[3]) << 16);
            unsigned int* dst =
                reinterpret_cast<unsigned int*>(&WhcT[(size_t)(b * DOUT + col - 128) * NTOK + nr]);
            dst[0] = p01;
            dst[1] = p23;
        }
    }
}

// ---------------------------------------------------------------- attn (split-K)
// grid (N/64, B, SPLIT), 256 thr. Wave w owns q-rows q0..q0+15; block covers
// keys [split*1024, split*1024+1024) in 16 LDS-staged 64-key tiles with
// reg-prefetch. Writes unnormalized partial O (bf16) + m,l per row.
__global__ __launch_bounds__(256) void attn_kernel(const unsigned short* __restrict__ Whs_hi,
                                                   const unsigned short* __restrict__ Whs_lo,
                                                   const unsigned short* __restrict__ Wht_hi,
                                                   const unsigned short* __restrict__ Wht_lo,
                                                   const unsigned short* __restrict__ WhcT,
                                                   const unsigned int* __restrict__ bits,
                                                   unsigned short* __restrict__ po,
                                                   float* __restrict__ pm,
                                                   float* __restrict__ pl) {
    __shared__ unsigned short Kh_lds[64][72];
    __shared__ unsigned short Kl_lds[64][72];
    __shared__ unsigned short V_lds[128][72];
    __shared__ unsigned short P_lds[4][16][72];

    int tid = threadIdx.x;
    int b = blockIdx.y;
    int split = blockIdx.z;
    int kbase = split * (NTOK / SPLIT);
    int w = tid >> 6, lane = tid & 63, lg = lane >> 4, lc = lane & 15;
    int q0 = blockIdx.x * 64 + w * 16;

    const unsigned short* qrowH = Whs_hi + (size_t)(b * NTOK + q0 + lc) * DHID;
    const unsigned short* qrowL = Whs_lo + (size_t)(b * NTOK + q0 + lc) * DHID;
    short8 qh0 = *reinterpret_cast<const short8*>(qrowH + lg * 8);
    short8 qh1 = *reinterpret_cast<const short8*>(qrowH + 32 + lg * 8);
    short8 ql0 = *reinterpret_cast<const short8*>(qrowL + lg * 8);
    short8 ql1 = *reinterpret_cast<const short8*>(qrowL + 32 + lg * 8);

    floatx4 o[8];
#pragma unroll
    for (int dt = 0; dt < 8; ++dt) o[dt] = (floatx4){0.f, 0.f, 0.f, 0.f};
    float m[4], l[4];
#pragma unroll
    for (int r = 0; r < 4; ++r) { m[r] = NEG_BIG; l[r] = 0.f; }

    // staging assignment
    int kkey = tid >> 2, koff = (tid & 3) * 16;
    int vd = tid >> 1, voff = (tid & 1) * 32;

    // prefetch registers
    short8 krH0, krH1, krL0, krL1, vr0, vr1, vr2, vr3;
    unsigned int mw0[4], mw1[4];

    // prologue: load tile 0
    {
        int kb = kbase;
        const unsigned short* ksrcH = Wht_hi + (size_t)(b * NTOK + kb + kkey) * DHID + koff;
        const unsigned short* ksrcL = Wht_lo + (size_t)(b * NTOK + kb + kkey) * DHID + koff;
        krH0 = *reinterpret_cast<const short8*>(ksrcH);
        krH1 = *reinterpret_cast<const short8*>(ksrcH + 8);
        krL0 = *reinterpret_cast<const short8*>(ksrcL);
        krL1 = *reinterpret_cast<const short8*>(ksrcL + 8);
        const unsigned short* vsrc = WhcT + (size_t)(b * DOUT + vd) * NTOK + kb + voff;
        vr0 = *reinterpret_cast<const short8*>(vsrc);
        vr1 = *reinterpret_cast<const short8*>(vsrc + 8);
        vr2 = *reinterpret_cast<const short8*>(vsrc + 16);
        vr3 = *reinterpret_cast<const short8*>(vsrc + 24);
#pragma unroll
        for (int r = 0; r < 4; ++r) {
            int n = q0 + 4 * lg + r;
            mw0[r] = bits[n * NWRD + (kb >> 5)];
            mw1[r] = bits[n * NWRD + (kb >> 5) + 1];
        }
    }

    for (int it = 0; it < ITERS; ++it) {
        __syncthreads();  // previous tile's compute done
        *reinterpret_cast<short8*>(&Kh_lds[kkey][koff]) = krH0;
        *reinterpret_cast<short8*>(&Kh_lds[kkey][koff + 8]) = krH1;
        *reinterpret_cast<short8*>(&Kl_lds[kkey][koff]) = krL0;
        *reinterpret_cast<short8*>(&Kl_lds[kkey][koff + 8]) = krL1;
        *reinterpret_cast<short8*>(&V_lds[vd][voff]) = vr0;
        *reinterpret_cast<short8*>(&V_lds[vd][voff + 8]) = vr1;
        *reinterpret_cast<short8*>(&V_lds[vd][voff + 16]) = vr2;
        *reinterpret_cast<short8*>(&V_lds[vd][voff + 24]) = vr3;
        __syncthreads();  // tile visible

        // S = Q K^T with hi/lo cross terms
        floatx4 s[4];
#pragma unroll
        for (int kc = 0; kc < 4; ++kc) {
            short8 kh0 = *reinterpret_cast<const short8*>(&Kh_lds[kc * 16 + lc][lg * 8]);
            short8 kh1 = *reinterpret_cast<const short8*>(&Kh_lds[kc * 16 + lc][32 + lg * 8]);
            short8 kl0 = *reinterpret_cast<const short8*>(&Kl_lds[kc * 16 + lc][lg * 8]);
            short8 kl1 = *reinterpret_cast<const short8*>(&Kl_lds[kc * 16 + lc][32 + lg * 8]);
            floatx4 acc = {0.f, 0.f, 0.f, 0.f};
            acc = mfma16(qh0, kh0, acc);
            acc = mfma16(qh1, kh1, acc);
            acc = mfma16(ql0, kh0, acc);
            acc = mfma16(ql1, kh1, acc);
            acc = mfma16(qh0, kl0, acc);
            acc = mfma16(qh1, kl1, acc);
            s[kc] = acc;
        }

        // adjacency mask (words were prefetched)
#pragma unroll
        for (int r = 0; r < 4; ++r) {
#pragma unroll
            for (int kc = 0; kc < 4; ++kc) {
                unsigned int word = (kc & 2) ? mw1[r] : mw0[r];
                int bit = ((kc & 1) * 16) + lc;
                if (!((word >> bit) & 1u)) s[kc][r] = NEG_BIG;
            }
        }

        // prefetch next tile (global -> reg, latency hidden under softmax+PV)
        if (it + 1 < ITERS) {
            int kb = kbase + (it + 1) * 64;
            const unsigned short* ksrcH = Wht_hi + (size_t)(b * NTOK + kb + kkey) * DHID + koff;
            const unsigned short* ksrcL = Wht_lo + (size_t)(b * NTOK + kb + kkey) * DHID + koff;
            krH0 = *reinterpret_cast<const short8*>(ksrcH);
            krH1 = *reinterpret_cast<const short8*>(ksrcH + 8);
            krL0 = *reinterpret_cast<const short8*>(ksrcL);
            krL1 = *reinterpret_cast<const short8*>(ksrcL + 8);
            const unsigned short* vsrc = WhcT + (size_t)(b * DOUT + vd) * NTOK + kb + voff;
            vr0 = *reinterpret_cast<const short8*>(vsrc);
            vr1 = *reinterpret_cast<const short8*>(vsrc + 8);
            vr2 = *reinterpret_cast<const short8*>(vsrc + 16);
            vr3 = *reinterpret_cast<const short8*>(vsrc + 24);
#pragma unroll
            for (int r = 0; r < 4; ++r) {
                int n = q0 + 4 * lg + r;
                mw0[r] = bits[n * NWRD + (kb >> 5)];
                mw1[r] = bits[n * NWRD + (kb >> 5) + 1];
            }
        }

        // online softmax
        float mn[4], sc[4], rs[4];
#pragma unroll
        for (int r = 0; r < 4; ++r) {
            float vm = fmaxf(fmaxf(s[0][r], s[1][r]), fmaxf(s[2][r], s[3][r]));
            vm = fmaxf(vm, __shfl_xor(vm, 1));
            vm = fmaxf(vm, __shfl_xor(vm, 2));
            vm = fmaxf(vm, __shfl_xor(vm, 4));
            vm = fmaxf(vm, __shfl_xor(vm, 8));
            float mnr = fmaxf(m[r], vm);
            sc[r] = __expf(m[r] - mnr);
            mn[r] = mnr;
            m[r] = mnr;
            rs[r] = 0.f;
        }
#pragma unroll
        for (int kc = 0; kc < 4; ++kc)
#pragma unroll
            for (int r = 0; r < 4; ++r) {
                float p = __expf(s[kc][r] - mn[r]);
                s[kc][r] = p;
                rs[r] += p;
            }
#pragma unroll
        for (int r = 0; r < 4; ++r) {
            float t = rs[r];
            t += __shfl_xor(t, 1);
            t += __shfl_xor(t, 2);
            t += __shfl_xor(t, 4);
            t += __shfl_xor(t, 8);
            l[r] = l[r] * sc[r] + t;
        }
#pragma unroll
        for (int dt = 0; dt < 8; ++dt)
#pragma unroll
            for (int r = 0; r < 4; ++r) o[dt][r] *= sc[r];

        // P -> LDS roundtrip for PV A-operand
#pragma unroll
        for (int kc = 0; kc < 4; ++kc)
#pragma unroll
            for (int r = 0; r < 4; ++r)
                P_lds[w][4 * lg + r][kc * 16 + lc] = f2bf(s[kc][r]);
        asm volatile("s_waitcnt lgkmcnt(0)" ::: "memory");
        __builtin_amdgcn_sched_barrier(0);
        short8 pa0 = *reinterpret_cast<const short8*>(&P_lds[w][lc][lg * 8]);
        short8 pa1 = *reinterpret_cast<const short8*>(&P_lds[w][lc][32 + lg * 8]);

#pragma unroll
        for (int dt = 0; dt < 8; ++dt) {
            short8 vf0 = *reinterpret_cast<const short8*>(&V_lds[dt * 16 + lc][lg * 8]);
            o[dt] = mfma16(pa0, vf0, o[dt]);
        }
#pragma unroll
        for (int dt = 0; dt < 8; ++dt) {
            short8 vf1 = *reinterpret_cast<const short8*>(&V_lds[dt * 16 + lc][32 + lg * 8]);
            o[dt] = mfma16(pa1, vf1, o[dt]);
        }
    }

    // epilogue: write partial (unnormalized O in bf16, m/l in f32)
#pragma unroll
    for (int r = 0; r < 4; ++r) {
        size_t row = (size_t)(split * BATCH + b) * NTOK + q0 + 4 * lg + r;
        unsigned short* prow = po + row * DOUT;
#pragma unroll
        for (int dt = 0; dt < 8; ++dt) prow[dt * 16 + lc] = f2bf(o[dt][r]);
        if (lc == 0) {
            pm[row] = m[r];
            pl[row] = l[r];
        }
    }
}

// ---------------------------------------------------------------- merge
__global__ __launch_bounds__(256) void merge_kernel(const unsigned short* __restrict__ po,
                                                    const float* __restrict__ pm,
                                                    const float* __restrict__ pl,
                                                    float* __restrict__ out) {
    int idx = blockIdx.x * 256 + threadIdx.x;  // 0 .. B*N*DOUT-1
    int d = idx & (DOUT - 1);
    size_t bn = (size_t)(idx >> 7);
    const size_t BN = (size_t)BATCH * NTOK;

    float ms[SPLIT];
#pragma unroll
    for (int s = 0; s < SPLIT; ++s) ms[s] = pm[s * BN + bn];
    float M = ms[0];
#pragma unroll
    for (int s = 1; s < SPLIT; ++s) M = fmaxf(M, ms[s]);
    float L = 0.f, acc = 0.f;
#pragma unroll
    for (int s = 0; s < SPLIT; ++s) {
        float e = __expf(ms[s] - M);
        L += pl[s * BN + bn] * e;
        acc += bf2f(po[(s * BN + bn) * DOUT + d]) * e;
    }
    out[idx] = acc / L;
}

// ---------------------------------------------------------------- launch
extern "C" void kernel_launch(void* const* d_in, const int* in_sizes, int n_in,
                              void* d_out, int out_size, void* d_ws, size_t ws_size,
                              hipStream_t stream) {
    const float* h   = (const float*)d_in[0];
    const int*   adj = (const int*)d_in[1];
    const float* Ws  = (const float*)d_in[2];
    const float* Wt  = (const float*)d_in[3];
    const float* Wc  = (const float*)d_in[4];
    float* out = (float*)d_out;

    // workspace layout (~31 MiB)
    size_t nq = (size_t)BATCH * NTOK * DHID;
    unsigned short* Whs_hi = (unsigned short*)d_ws;                                // 2 MiB
    unsigned short* Whs_lo = Whs_hi + nq;                                          // 2 MiB
    unsigned short* Wht_hi = Whs_lo + nq;                                          // 2 MiB
    unsigned short* Wht_lo = Wht_hi + nq;                                          // 2 MiB
    unsigned short* WhcT   = Wht_lo + nq;                                          // 4 MiB
    unsigned int*   bits   = (unsigned int*)(WhcT + (size_t)BATCH * DOUT * NTOK);  // 2 MiB
    unsigned short* WT_hi  = (unsigned short*)(bits + (size_t)NTOK * NWRD);        // 64 KiB
    unsigned short* WT_lo  = WT_hi + 256 * DIN;                                    // 32 KiB
    unsigned short* po     = WT_lo + 128 * DIN;                                    // 16 MiB
    float*          pm     = (float*)(po + (size_t)SPLIT * BATCH * NTOK * DOUT);   // 256 KiB
    float*          pl     = pm + (size_t)SPLIT * BATCH * NTOK;                    // 256 KiB

    pack_adj_kernel<<<dim3(NTOK * NWRD / 256), dim3(256), 0, stream>>>(adj, bits);
    conv_w_kernel<<<dim3(128), dim3(256), 0, stream>>>(Ws, Wt, Wc, WT_hi, WT_lo);
    prep_kernel<<<dim3(NTOK / 16, BATCH), dim3(256), 0, stream>>>(
        h, WT_hi, WT_lo, Whs_hi, Whs_lo, Wht_hi, Wht_lo, WhcT);
    attn_kernel<<<dim3(NTOK / 64, BATCH, SPLIT), dim3(256), 0, stream>>>(
        Whs_hi, Whs_lo, Wht_hi, Wht_lo, WhcT, bits, po, pm, pl);
    merge_kernel<<<dim3(BATCH * NTOK * DOUT / 256), dim3(256), 0, stream>>>(po, pm, pl, out);
}

// Round 4
// 221.984 us; speedup vs baseline: 1.2181x; 1.0370x over previous
//
#include <hip/hip_runtime.h>
#include <hip/hip_bf16.h>

// GraphAttentionLayer = flash attention with adjacency mask.
// B=4, N=4096, D_in=128, H=64 (QK dim), D_out=128 (V dim).
// Precision: scores need ~f32 accuracy (softmax amplifies bf16 rounding of
// +-70-magnitude scores) -> Whs/Wht GEMM and QK^T use bf16 hi+lo 3-term MFMA.
// P, V, partial-O are single bf16 (lands well under the 8-ulp output floor).
// Structure: split-K flash (SPLIT=4, 1024 blocks = 4/CU, LDS 36 KB) with
// swapped QK^T (mfma(K,Q): lane's lc = its q-row -> lane-local softmax) and a
// permuted V slot order in LDS so the PV A-fragment is packed in-register
// from the QK output (no P LDS roundtrip, no shuffles).
#define NTOK 4096
#define BATCH 4
#define DIN 128
#define DHID 64
#define DOUT 128
#define NWRD (NTOK / 32)
#define SPLIT 4
#define ITERS (NTOK / SPLIT / 64)  // 16 key-tiles per split
#define NEG_BIG -9.0e15f

typedef short short8 __attribute__((ext_vector_type(8)));
typedef short short4v __attribute__((ext_vector_type(4)));
typedef float floatx4 __attribute__((ext_vector_type(4)));

static __device__ __forceinline__ unsigned short f2bf(float f) {
    unsigned int u = __builtin_bit_cast(unsigned int, f);
    u = (u + 0x7fffu + ((u >> 16) & 1u)) >> 16;
    return (unsigned short)u;
}
static __device__ __forceinline__ float bf2f(unsigned short s) {
    unsigned int u = ((unsigned int)s) << 16;
    return __builtin_bit_cast(float, u);
}
// pack two f32 -> (lo,hi) bf16 in one u32 (T12 recipe, proven on gfx950)
static __device__ __forceinline__ unsigned int pk2(float lo, float hi) {
    unsigned int r;
    asm("v_cvt_pk_bf16_f32 %0, %1, %2" : "=v"(r) : "v"(lo), "v"(hi));
    return r;
}

static __device__ __forceinline__ floatx4 mfma16(short8 a, short8 b, floatx4 c) {
    // v_mfma_f32_16x16x32_bf16: A row = lane&15, k = 8*(lane>>4)+{0..7}
    //                           B col = lane&15, k = 8*(lane>>4)+{0..7}
    //                           D col = lane&15, row = 4*(lane>>4)+reg
    return __builtin_amdgcn_mfma_f32_16x16x32_bf16(a, b, c, 0, 0, 0);
}

// ---------------------------------------------------------------- pack_adj
__global__ __launch_bounds__(256) void pack_adj_kernel(const int* __restrict__ adj,
                                                       unsigned int* __restrict__ bits) {
    int w = blockIdx.x * 256 + threadIdx.x;
    const int4* p = reinterpret_cast<const int4*>(adj) + (size_t)w * 8;
    unsigned int m = 0;
#pragma unroll
    for (int i = 0; i < 8; ++i) {
        int4 v = p[i];
        m |= (v.x > 0 ? 1u : 0u) << (4 * i + 0);
        m |= (v.y > 0 ? 1u : 0u) << (4 * i + 1);
        m |= (v.z > 0 ? 1u : 0u) << (4 * i + 2);
        m |= (v.w > 0 ? 1u : 0u) << (4 * i + 3);
    }
    bits[w] = m;
}

// ---------------------------------------------------------------- conv_w
__global__ __launch_bounds__(256) void conv_w_kernel(const float* __restrict__ Ws,
                                                     const float* __restrict__ Wt,
                                                     const float* __restrict__ Wc,
                                                     unsigned short* __restrict__ WT_hi,
                                                     unsigned short* __restrict__ WT_lo) {
    int idx = blockIdx.x * 256 + threadIdx.x;
    int k = idx >> 8, col = idx & 255;
    float w;
    if (col < 64) w = Ws[k * DHID + col];
    else if (col < 128) w = Wt[k * DHID + (col - 64)];
    else w = Wc[k * DOUT + (col - 128)];
    unsigned short hi = f2bf(w);
    WT_hi[col * DIN + k] = hi;
    if (col < 128) WT_lo[col * DIN + k] = f2bf(w - bf2f(hi));
}

// ---------------------------------------------------------------- prep
// grid (N/16, B), 256 thr. Wave w owns 64 cols: w0->Whs (3-term), w1->Wht
// (3-term), w2/w3 -> Whc (hi only, stored transposed WhcT[b][d][n]).
__global__ __launch_bounds__(256) void prep_kernel(const float* __restrict__ h,
                                                   const unsigned short* __restrict__ WT_hi,
                                                   const unsigned short* __restrict__ WT_lo,
                                                   unsigned short* __restrict__ Whs_hi,
                                                   unsigned short* __restrict__ Whs_lo,
                                                   unsigned short* __restrict__ Wht_hi,
                                                   unsigned short* __restrict__ Wht_lo,
                                                   unsigned short* __restrict__ WhcT) {
    int tid = threadIdx.x;
    int b = blockIdx.y;
    int w = tid >> 6, lane = tid & 63, lg = lane >> 4, lc = lane & 15;
    int n0 = blockIdx.x * 16;
    const float* hrow = h + (size_t)(b * NTOK + n0 + lc) * DIN;

    short8 ah[4], al[4];
#pragma unroll
    for (int ks = 0; ks < 4; ++ks) {
        float4 f0 = *reinterpret_cast<const float4*>(hrow + ks * 32 + lg * 8);
        float4 f1 = *reinterpret_cast<const float4*>(hrow + ks * 32 + lg * 8 + 4);
        float x[8] = {f0.x, f0.y, f0.z, f0.w, f1.x, f1.y, f1.z, f1.w};
        short8 hh, ll;
#pragma unroll
        for (int j = 0; j < 8; ++j) {
            unsigned short hb = f2bf(x[j]);
            hh[j] = (short)hb;
            ll[j] = (short)f2bf(x[j] - bf2f(hb));
        }
        ah[ks] = hh;
        al[ks] = ll;
    }

#pragma unroll
    for (int ci = 0; ci < 4; ++ci) {
        int ct = w * 4 + ci;
        int col = ct * 16 + lc;
        const unsigned short* bbase = WT_hi + (size_t)col * DIN;
        const unsigned short* lbase = WT_lo + (size_t)col * DIN;
        floatx4 acc = {0.f, 0.f, 0.f, 0.f};
#pragma unroll
        for (int ks = 0; ks < 4; ++ks) {
            short8 bh = *reinterpret_cast<const short8*>(bbase + ks * 32 + lg * 8);
            acc = mfma16(ah[ks], bh, acc);
            if (w < 2) {
                short8 bl = *reinterpret_cast<const short8*>(lbase + ks * 32 + lg * 8);
                acc = mfma16(ah[ks], bl, acc);
                acc = mfma16(al[ks], bh, acc);
            }
        }
        int nr = n0 + 4 * lg;
        if (w == 0) {
#pragma unroll
            for (int r = 0; r < 4; ++r) {
                float v = acc[r];
                unsigned short hb = f2bf(v);
                size_t o = (size_t)(b * NTOK + nr + r) * DHID + col;
                Whs_hi[o] = hb;
                Whs_lo[o] = f2bf(v - bf2f(hb));
            }
        } else if (w == 1) {
#pragma unroll
            for (int r = 0; r < 4; ++r) {
                float v = acc[r];
                unsigned short hb = f2bf(v);
                size_t o = (size_t)(b * NTOK + nr + r) * DHID + (col - 64);
                Wht_hi[o] = hb;
                Wht_lo[o] = f2bf(v - bf2f(hb));
            }
        } else {
            unsigned int p01 = (unsigned int)f2bf(acc[0]) | ((unsigned int)f2bf(acc[1]) << 16);
            unsigned int p23 = (unsigned int)f2bf(acc[2]) | ((unsigned int)f2bf(acc[3]) << 16);
            unsigned int* dst =
                reinterpret_cast<unsigned int*>(&WhcT[(size_t)(b * DOUT + col - 128) * NTOK + nr]);
            dst[0] = p01;
            dst[1] = p23;
        }
    }
}

// ---------------------------------------------------------------- attn (split-K)
// grid (N/64, B, SPLIT), 256 thr, 4 blocks/CU (LDS 36 KB, VGPR capped by
// launch_bounds). Swapped QK^T: s[kc][r] = score(q = q0+lc, key = 16kc+4lg+r).
// V staged with permuted key slots: slot(k) = 16k3+8k2+4k4+2k1+k0 so that the
// PV A-operand (k = 8*lg+j) equals in-lane P values p[j>>2][j&3].
__global__ __launch_bounds__(256, 4) void attn_kernel(const unsigned short* __restrict__ Whs_hi,
                                                      const unsigned short* __restrict__ Whs_lo,
                                                      const unsigned short* __restrict__ Wht_hi,
                                                      const unsigned short* __restrict__ Wht_lo,
                                                      const unsigned short* __restrict__ WhcT,
                                                      const unsigned int* __restrict__ bits,
                                                      unsigned short* __restrict__ po,
                                                      float* __restrict__ pm,
                                                      float* __restrict__ pl) {
    __shared__ unsigned short Kh_lds[64][72];
    __shared__ unsigned short Kl_lds[64][72];
    __shared__ unsigned short V_lds[128][72];  // [d][slot], permuted slots

    int tid = threadIdx.x;
    int b = blockIdx.y;
    int split = blockIdx.z;
    int kbase = split * (NTOK / SPLIT);
    int lane = tid & 63, lg = lane >> 4, lc = lane & 15;
    int q0 = blockIdx.x * 64 + (tid >> 6) * 16;
    int n = q0 + lc;  // this lane's q-row

    // Q fragments as MFMA B operand: col = lc = q, k = h
    const unsigned short* qrowH = Whs_hi + (size_t)(b * NTOK + n) * DHID;
    const unsigned short* qrowL = Whs_lo + (size_t)(b * NTOK + n) * DHID;
    short8 qh0 = *reinterpret_cast<const short8*>(qrowH + lg * 8);
    short8 qh1 = *reinterpret_cast<const short8*>(qrowH + 32 + lg * 8);
    short8 ql0 = *reinterpret_cast<const short8*>(qrowL + lg * 8);
    short8 ql1 = *reinterpret_cast<const short8*>(qrowL + 32 + lg * 8);

    floatx4 o[8];
#pragma unroll
    for (int dt = 0; dt < 8; ++dt) o[dt] = (floatx4){0.f, 0.f, 0.f, 0.f};
    float m = NEG_BIG, l = 0.f;

    // staging assignment
    int kkey = tid >> 2, koff = (tid & 3) * 16;
    int vd = tid >> 1, va = tid & 1;  // V: thread loads keys 32*va..+31 of row vd

    short8 krH0, krH1, krL0, krL1, vr0, vr1, vr2, vr3;
    unsigned int mw0, mw1;

    {  // prologue: load tile 0
        int kb = kbase;
        const unsigned short* ksrcH = Wht_hi + (size_t)(b * NTOK + kb + kkey) * DHID + koff;
        const unsigned short* ksrcL = Wht_lo + (size_t)(b * NTOK + kb + kkey) * DHID + koff;
        krH0 = *reinterpret_cast<const short8*>(ksrcH);
        krH1 = *reinterpret_cast<const short8*>(ksrcH + 8);
        krL0 = *reinterpret_cast<const short8*>(ksrcL);
        krL1 = *reinterpret_cast<const short8*>(ksrcL + 8);
        const unsigned short* vsrc = WhcT + (size_t)(b * DOUT + vd) * NTOK + kb + va * 32;
        vr0 = *reinterpret_cast<const short8*>(vsrc);
        vr1 = *reinterpret_cast<const short8*>(vsrc + 8);
        vr2 = *reinterpret_cast<const short8*>(vsrc + 16);
        vr3 = *reinterpret_cast<const short8*>(vsrc + 24);
        mw0 = bits[n * NWRD + (kb >> 5)];
        mw1 = bits[n * NWRD + (kb >> 5) + 1];
    }

    for (int it = 0; it < ITERS; ++it) {
        __syncthreads();  // previous tile's compute done
        *reinterpret_cast<short8*>(&Kh_lds[kkey][koff]) = krH0;
        *reinterpret_cast<short8*>(&Kh_lds[kkey][koff + 8]) = krH1;
        *reinterpret_cast<short8*>(&Kl_lds[kkey][koff]) = krL0;
        *reinterpret_cast<short8*>(&Kl_lds[kkey][koff + 8]) = krL1;
        // V permuted-slot writes: vr j covers keys 32*va+8j..+7; half h is a
        // short4 at slot 32*va + 16*(j&1) + 8*h + 4*(j>>1).
        {
            int sb = va * 32;
            const short8 vv[4] = {vr0, vr1, vr2, vr3};
#pragma unroll
            for (int j = 0; j < 4; ++j) {
                short4v lo4 = {vv[j][0], vv[j][1], vv[j][2], vv[j][3]};
                short4v hi4 = {vv[j][4], vv[j][5], vv[j][6], vv[j][7]};
                int s0 = sb + 16 * (j & 1) + 4 * (j >> 1);
                *reinterpret_cast<short4v*>(&V_lds[vd][s0]) = lo4;
                *reinterpret_cast<short4v*>(&V_lds[vd][s0 + 8]) = hi4;
            }
        }
        __syncthreads();  // tile visible

        // S^T = K Q^T with hi/lo cross terms: col=lc=q, row=4lg+r=key%16
        floatx4 s[4];
        __builtin_amdgcn_s_setprio(1);
#pragma unroll
        for (int kc = 0; kc < 4; ++kc) {
            short8 kh0 = *reinterpret_cast<const short8*>(&Kh_lds[kc * 16 + lc][lg * 8]);
            short8 kh1 = *reinterpret_cast<const short8*>(&Kh_lds[kc * 16 + lc][32 + lg * 8]);
            short8 kl0 = *reinterpret_cast<const short8*>(&Kl_lds[kc * 16 + lc][lg * 8]);
            short8 kl1 = *reinterpret_cast<const short8*>(&Kl_lds[kc * 16 + lc][32 + lg * 8]);
            floatx4 acc = {0.f, 0.f, 0.f, 0.f};
            acc = mfma16(kh0, qh0, acc);
            acc = mfma16(kh1, qh1, acc);
            acc = mfma16(kh0, ql0, acc);
            acc = mfma16(kh1, ql1, acc);
            acc = mfma16(kl0, qh0, acc);
            acc = mfma16(kl1, qh1, acc);
            s[kc] = acc;
        }
        __builtin_amdgcn_s_setprio(0);

        // adjacency mask: key = 16kc+4lg+r -> word kc>>1, bit 16*(kc&1)+4lg+r
#pragma unroll
        for (int kc = 0; kc < 4; ++kc) {
            unsigned int word = (kc & 2) ? mw1 : mw0;
#pragma unroll
            for (int r = 0; r < 4; ++r) {
                int bit = 16 * (kc & 1) + 4 * lg + r;
                if (!((word >> bit) & 1u)) s[kc][r] = NEG_BIG;
            }
        }

        // prefetch next tile (global -> reg, hidden under softmax+PV)
        if (it + 1 < ITERS) {
            int kb = kbase + (it + 1) * 64;
            const unsigned short* ksrcH = Wht_hi + (size_t)(b * NTOK + kb + kkey) * DHID + koff;
            const unsigned short* ksrcL = Wht_lo + (size_t)(b * NTOK + kb + kkey) * DHID + koff;
            krH0 = *reinterpret_cast<const short8*>(ksrcH);
            krH1 = *reinterpret_cast<const short8*>(ksrcH + 8);
            krL0 = *reinterpret_cast<const short8*>(ksrcL);
            krL1 = *reinterpret_cast<const short8*>(ksrcL + 8);
            const unsigned short* vsrc = WhcT + (size_t)(b * DOUT + vd) * NTOK + kb + va * 32;
            vr0 = *reinterpret_cast<const short8*>(vsrc);
            vr1 = *reinterpret_cast<const short8*>(vsrc + 8);
            vr2 = *reinterpret_cast<const short8*>(vsrc + 16);
            vr3 = *reinterpret_cast<const short8*>(vsrc + 24);
            mw0 = bits[n * NWRD + (kb >> 5)];
            mw1 = bits[n * NWRD + (kb >> 5) + 1];
        }

        // online softmax, q = lc (mostly lane-local; keys spread over lg)
        float vm = s[0][0];
#pragma unroll
        for (int kc = 0; kc < 4; ++kc)
#pragma unroll
            for (int r = 0; r < 4; ++r) vm = fmaxf(vm, s[kc][r]);
        vm = fmaxf(vm, __shfl_xor(vm, 16));
        vm = fmaxf(vm, __shfl_xor(vm, 32));
        float mn = fmaxf(m, vm);
        float sc = __expf(m - mn);
        m = mn;
        float rs = 0.f;
#pragma unroll
        for (int kc = 0; kc < 4; ++kc)
#pragma unroll
            for (int r = 0; r < 4; ++r) {
                float p = __expf(s[kc][r] - mn);
                s[kc][r] = p;
                rs += p;
            }
        rs += __shfl_xor(rs, 16);
        rs += __shfl_xor(rs, 32);
        l = l * sc + rs;

        // o rescale needs sc at q=4lg+r (o rows), sc lives at q=lc
        float sc4[4];
#pragma unroll
        for (int r = 0; r < 4; ++r) sc4[r] = __shfl(sc, (lane & 48) + 4 * lg + r);
#pragma unroll
        for (int dt = 0; dt < 8; ++dt)
#pragma unroll
            for (int r = 0; r < 4; ++r) o[dt][r] *= sc4[r];

        // pack PV A-operand in-register (V slot permutation makes this exact)
        unsigned int pw[8];
        pw[0] = pk2(s[0][0], s[0][1]); pw[1] = pk2(s[0][2], s[0][3]);
        pw[2] = pk2(s[1][0], s[1][1]); pw[3] = pk2(s[1][2], s[1][3]);
        pw[4] = pk2(s[2][0], s[2][1]); pw[5] = pk2(s[2][2], s[2][3]);
        pw[6] = pk2(s[3][0], s[3][1]); pw[7] = pk2(s[3][2], s[3][3]);
        short8 pa0 = __builtin_bit_cast(short8, *reinterpret_cast<uint4*>(&pw[0]));
        short8 pa1 = __builtin_bit_cast(short8, *reinterpret_cast<uint4*>(&pw[4]));

        // O += P V  (B col = lc = d, k = permuted slots)
        __builtin_amdgcn_s_setprio(1);
#pragma unroll
        for (int dt = 0; dt < 8; ++dt) {
            short8 vf0 = *reinterpret_cast<const short8*>(&V_lds[dt * 16 + lc][lg * 8]);
            o[dt] = mfma16(pa0, vf0, o[dt]);
        }
#pragma unroll
        for (int dt = 0; dt < 8; ++dt) {
            short8 vf1 = *reinterpret_cast<const short8*>(&V_lds[dt * 16 + lc][32 + lg * 8]);
            o[dt] = mfma16(pa1, vf1, o[dt]);
        }
        __builtin_amdgcn_s_setprio(0);
    }

    // epilogue: o rows are q=4lg+r; softmax state is q=lc -> shfl it over
    float m4[4], l4[4];
#pragma unroll
    for (int r = 0; r < 4; ++r) {
        int src = (lane & 48) + 4 * lg + r;
        m4[r] = __shfl(m, src);
        l4[r] = __shfl(l, src);
    }
#pragma unroll
    for (int r = 0; r < 4; ++r) {
        size_t row = (size_t)(split * BATCH + b) * NTOK + q0 + 4 * lg + r;
        unsigned short* prow = po + row * DOUT;
#pragma unroll
        for (int dt = 0; dt < 8; ++dt) prow[dt * 16 + lc] = f2bf(o[dt][r]);
        if (lc == 0) {
            pm[row] = m4[r];
            pl[row] = l4[r];
        }
    }
}

// ---------------------------------------------------------------- merge
__global__ __launch_bounds__(256) void merge_kernel(const unsigned short* __restrict__ po,
                                                    const float* __restrict__ pm,
                                                    const float* __restrict__ pl,
                                                    float* __restrict__ out) {
    int idx = blockIdx.x * 256 + threadIdx.x;
    int d = idx & (DOUT - 1);
    size_t bn = (size_t)(idx >> 7);
    const size_t BN = (size_t)BATCH * NTOK;

    float ms[SPLIT];
#pragma unroll
    for (int s = 0; s < SPLIT; ++s) ms[s] = pm[s * BN + bn];
    float M = ms[0];
#pragma unroll
    for (int s = 1; s < SPLIT; ++s) M = fmaxf(M, ms[s]);
    float L = 0.f, acc = 0.f;
#pragma unroll
    for (int s = 0; s < SPLIT; ++s) {
        float e = __expf(ms[s] - M);
        L += pl[s * BN + bn] * e;
        acc += bf2f(po[(s * BN + bn) * DOUT + d]) * e;
    }
    out[idx] = acc / L;
}

// ---------------------------------------------------------------- launch
extern "C" void kernel_launch(void* const* d_in, const int* in_sizes, int n_in,
                              void* d_out, int out_size, void* d_ws, size_t ws_size,
                              hipStream_t stream) {
    const float* h   = (const float*)d_in[0];
    const int*   adj = (const int*)d_in[1];
    const float* Ws  = (const float*)d_in[2];
    const float* Wt  = (const float*)d_in[3];
    const float* Wc  = (const float*)d_in[4];
    float* out = (float*)d_out;

    // workspace layout (~31 MiB)
    size_t nq = (size_t)BATCH * NTOK * DHID;
    unsigned short* Whs_hi = (unsigned short*)d_ws;                                // 2 MiB
    unsigned short* Whs_lo = Whs_hi + nq;                                          // 2 MiB
    unsigned short* Wht_hi = Whs_lo + nq;                                          // 2 MiB
    unsigned short* Wht_lo = Wht_hi + nq;                                          // 2 MiB
    unsigned short* WhcT   = Wht_lo + nq;                                          // 4 MiB
    unsigned int*   bits   = (unsigned int*)(WhcT + (size_t)BATCH * DOUT * NTOK);  // 2 MiB
    unsigned short* WT_hi  = (unsigned short*)(bits + (size_t)NTOK * NWRD);        // 64 KiB
    unsigned short* WT_lo  = WT_hi + 256 * DIN;                                    // 32 KiB
    unsigned short* po     = WT_lo + 128 * DIN;                                    // 16 MiB
    float*          pm     = (float*)(po + (size_t)SPLIT * BATCH * NTOK * DOUT);   // 256 KiB
    float*          pl     = pm + (size_t)SPLIT * BATCH * NTOK;                    // 256 KiB

    pack_adj_kernel<<<dim3(NTOK * NWRD / 256), dim3(256), 0, stream>>>(adj, bits);
    conv_w_kernel<<<dim3(128), dim3(256), 0, stream>>>(Ws, Wt, Wc, WT_hi, WT_lo);
    prep_kernel<<<dim3(NTOK / 16, BATCH), dim3(256), 0, stream>>>(
        h, WT_hi, WT_lo, Whs_hi, Whs_lo, Wht_hi, Wht_lo, WhcT);
    attn_kernel<<<dim3(NTOK / 64, BATCH, SPLIT), dim3(256), 0, stream>>>(
        Whs_hi, Whs_lo, Wht_hi, Wht_lo, WhcT, bits, po, pm, pl);
    merge_kernel<<<dim3(BATCH * NTOK * DOUT / 256), dim3(256), 0, stream>>>(po, pm, pl, out);
}

// Round 5
// 189.492 us; speedup vs baseline: 1.4269x; 1.1715x over previous
//
#include <hip/hip_runtime.h>
#include <hip/hip_bf16.h>

// GraphAttentionLayer = flash attention with adjacency mask.
// B=4, N=4096, D_in=128, H=64 (QK dim), D_out=128 (V dim).
// Precision: scores need ~f32 accuracy (softmax amplifies bf16 rounding of
// +-70-magnitude scores) -> Whs/Wht GEMM and QK^T use bf16 hi+lo 3-term MFMA.
// P, V, partial-O are single bf16 (lands well under the 8-ulp output floor).
// Structure: split-K flash (SPLIT=4), 512 blocks = exactly 2/CU, 36 KB LDS.
// Each wave owns 32 q-rows (two 16-q groups) so every K/V fragment read from
// LDS feeds 2 MFMAs -> LDS bytes/FLOP halved vs 16q/wave (round-4 bottleneck).
// Swapped QK^T (mfma(K,Q): lane's lc = q-row -> lane-local softmax); V staged
// with permuted key slots so the PV A-operand is packed in-register from the
// QK output via v_cvt_pk_bf16_f32 (no P LDS roundtrip, no shuffles).
#define NTOK 4096
#define BATCH 4
#define DIN 128
#define DHID 64
#define DOUT 128
#define NWRD (NTOK / 32)
#define SPLIT 4
#define ITERS (NTOK / SPLIT / 64)  // 16 key-tiles per split
#define NEG_BIG -9.0e15f

typedef short short8 __attribute__((ext_vector_type(8)));
typedef float floatx4 __attribute__((ext_vector_type(4)));

static __device__ __forceinline__ unsigned short f2bf(float f) {
    unsigned int u = __builtin_bit_cast(unsigned int, f);
    u = (u + 0x7fffu + ((u >> 16) & 1u)) >> 16;
    return (unsigned short)u;
}
static __device__ __forceinline__ float bf2f(unsigned short s) {
    unsigned int u = ((unsigned int)s) << 16;
    return __builtin_bit_cast(float, u);
}
// pack two f32 -> (lo,hi) bf16 in one u32
static __device__ __forceinline__ unsigned int pk2(float lo, float hi) {
    unsigned int r;
    asm("v_cvt_pk_bf16_f32 %0, %1, %2" : "=v"(r) : "v"(lo), "v"(hi));
    return r;
}

static __device__ __forceinline__ floatx4 mfma16(short8 a, short8 b, floatx4 c) {
    // v_mfma_f32_16x16x32_bf16: A row = lane&15, k = 8*(lane>>4)+{0..7}
    //                           B col = lane&15, k = 8*(lane>>4)+{0..7}
    //                           D col = lane&15, row = 4*(lane>>4)+reg
    return __builtin_amdgcn_mfma_f32_16x16x32_bf16(a, b, c, 0, 0, 0);
}

// ---------------------------------------------------------------- pack_adj
__global__ __launch_bounds__(256) void pack_adj_kernel(const int* __restrict__ adj,
                                                       unsigned int* __restrict__ bits) {
    int w = blockIdx.x * 256 + threadIdx.x;
    const int4* p = reinterpret_cast<const int4*>(adj) + (size_t)w * 8;
    unsigned int m = 0;
#pragma unroll
    for (int i = 0; i < 8; ++i) {
        int4 v = p[i];
        m |= (v.x > 0 ? 1u : 0u) << (4 * i + 0);
        m |= (v.y > 0 ? 1u : 0u) << (4 * i + 1);
        m |= (v.z > 0 ? 1u : 0u) << (4 * i + 2);
        m |= (v.w > 0 ? 1u : 0u) << (4 * i + 3);
    }
    bits[w] = m;
}

// ---------------------------------------------------------------- conv_w
__global__ __launch_bounds__(256) void conv_w_kernel(const float* __restrict__ Ws,
                                                     const float* __restrict__ Wt,
                                                     const float* __restrict__ Wc,
                                                     unsigned short* __restrict__ WT_hi,
                                                     unsigned short* __restrict__ WT_lo) {
    int idx = blockIdx.x * 256 + threadIdx.x;
    int k = idx >> 8, col = idx & 255;
    float w;
    if (col < 64) w = Ws[k * DHID + col];
    else if (col < 128) w = Wt[k * DHID + (col - 64)];
    else w = Wc[k * DOUT + (col - 128)];
    unsigned short hi = f2bf(w);
    WT_hi[col * DIN + k] = hi;
    if (col < 128) WT_lo[col * DIN + k] = f2bf(w - bf2f(hi));
}

// ---------------------------------------------------------------- prep
__global__ __launch_bounds__(256) void prep_kernel(const float* __restrict__ h,
                                                   const unsigned short* __restrict__ WT_hi,
                                                   const unsigned short* __restrict__ WT_lo,
                                                   unsigned short* __restrict__ Whs_hi,
                                                   unsigned short* __restrict__ Whs_lo,
                                                   unsigned short* __restrict__ Wht_hi,
                                                   unsigned short* __restrict__ Wht_lo,
                                                   unsigned short* __restrict__ WhcT) {
    int tid = threadIdx.x;
    int b = blockIdx.y;
    int w = tid >> 6, lane = tid & 63, lg = lane >> 4, lc = lane & 15;
    int n0 = blockIdx.x * 16;
    const float* hrow = h + (size_t)(b * NTOK + n0 + lc) * DIN;

    short8 ah[4], al[4];
#pragma unroll
    for (int ks = 0; ks < 4; ++ks) {
        float4 f0 = *reinterpret_cast<const float4*>(hrow + ks * 32 + lg * 8);
        float4 f1 = *reinterpret_cast<const float4*>(hrow + ks * 32 + lg * 8 + 4);
        float x[8] = {f0.x, f0.y, f0.z, f0.w, f1.x, f1.y, f1.z, f1.w};
        short8 hh, ll;
#pragma unroll
        for (int j = 0; j < 8; ++j) {
            unsigned short hb = f2bf(x[j]);
            hh[j] = (short)hb;
            ll[j] = (short)f2bf(x[j] - bf2f(hb));
        }
        ah[ks] = hh;
        al[ks] = ll;
    }

#pragma unroll
    for (int ci = 0; ci < 4; ++ci) {
        int ct = w * 4 + ci;
        int col = ct * 16 + lc;
        const unsigned short* bbase = WT_hi + (size_t)col * DIN;
        const unsigned short* lbase = WT_lo + (size_t)col * DIN;
        floatx4 acc = {0.f, 0.f, 0.f, 0.f};
#pragma unroll
        for (int ks = 0; ks < 4; ++ks) {
            short8 bh = *reinterpret_cast<const short8*>(bbase + ks * 32 + lg * 8);
            acc = mfma16(ah[ks], bh, acc);
            if (w < 2) {
                short8 bl = *reinterpret_cast<const short8*>(lbase + ks * 32 + lg * 8);
                acc = mfma16(ah[ks], bl, acc);
                acc = mfma16(al[ks], bh, acc);
            }
        }
        int nr = n0 + 4 * lg;
        if (w == 0) {
#pragma unroll
            for (int r = 0; r < 4; ++r) {
                float v = acc[r];
                unsigned short hb = f2bf(v);
                size_t o = (size_t)(b * NTOK + nr + r) * DHID + col;
                Whs_hi[o] = hb;
                Whs_lo[o] = f2bf(v - bf2f(hb));
            }
        } else if (w == 1) {
#pragma unroll
            for (int r = 0; r < 4; ++r) {
                float v = acc[r];
                unsigned short hb = f2bf(v);
                size_t o = (size_t)(b * NTOK + nr + r) * DHID + (col - 64);
                Wht_hi[o] = hb;
                Wht_lo[o] = f2bf(v - bf2f(hb));
            }
        } else {
            unsigned int p01 = (unsigned int)f2bf(acc[0]) | ((unsigned int)f2bf(acc[1]) << 16);
            unsigned int p23 = (unsigned int)f2bf(acc[2]) | ((unsigned int)f2bf(acc[3]) << 16);
            unsigned int* dst =
                reinterpret_cast<unsigned int*>(&WhcT[(size_t)(b * DOUT + col - 128) * NTOK + nr]);
            dst[0] = p01;
            dst[1] = p23;
        }
    }
}

// ---------------------------------------------------------------- attn (split-K)
// grid (N/128, B, SPLIT), 256 thr, 2 blocks/CU. Wave owns 32 q-rows (groups
// A: q0+lc, B: q0+16+lc). s[kc][r] = score(q, key=16kc+4lg+r). V slots
// permuted: slot(32a+8j+4h+t) = 32a+16(j&1)+8h+4(j>>1)+t so PV A-operand ==
// in-lane packed P.
__global__ __launch_bounds__(256, 2) void attn_kernel(const unsigned short* __restrict__ Whs_hi,
                                                      const unsigned short* __restrict__ Whs_lo,
                                                      const unsigned short* __restrict__ Wht_hi,
                                                      const unsigned short* __restrict__ Wht_lo,
                                                      const unsigned short* __restrict__ WhcT,
                                                      const unsigned int* __restrict__ bits,
                                                      unsigned short* __restrict__ po,
                                                      float* __restrict__ pm,
                                                      float* __restrict__ pl) {
    __shared__ unsigned short Kh_lds[64][72];
    __shared__ unsigned short Kl_lds[64][72];
    __shared__ unsigned short V_lds[128][72];  // [d][slot], permuted slots

    int tid = threadIdx.x;
    int b = blockIdx.y;
    int split = blockIdx.z;
    int kbase = split * (NTOK / SPLIT);
    int lane = tid & 63, lg = lane >> 4, lc = lane & 15;
    int q0 = blockIdx.x * 128 + (tid >> 6) * 32;
    int nA = q0 + lc, nB = q0 + 16 + lc;

    // Q fragments (B-operand: col = lc = q, k = h) for both q-groups
    const unsigned short* qAH = Whs_hi + (size_t)(b * NTOK + nA) * DHID;
    const unsigned short* qAL = Whs_lo + (size_t)(b * NTOK + nA) * DHID;
    const unsigned short* qBH = Whs_hi + (size_t)(b * NTOK + nB) * DHID;
    const unsigned short* qBL = Whs_lo + (size_t)(b * NTOK + nB) * DHID;
    short8 qAh0 = *reinterpret_cast<const short8*>(qAH + lg * 8);
    short8 qAh1 = *reinterpret_cast<const short8*>(qAH + 32 + lg * 8);
    short8 qAl0 = *reinterpret_cast<const short8*>(qAL + lg * 8);
    short8 qAl1 = *reinterpret_cast<const short8*>(qAL + 32 + lg * 8);
    short8 qBh0 = *reinterpret_cast<const short8*>(qBH + lg * 8);
    short8 qBh1 = *reinterpret_cast<const short8*>(qBH + 32 + lg * 8);
    short8 qBl0 = *reinterpret_cast<const short8*>(qBL + lg * 8);
    short8 qBl1 = *reinterpret_cast<const short8*>(qBL + 32 + lg * 8);

    floatx4 o0[8], o1[8];
#pragma unroll
    for (int dt = 0; dt < 8; ++dt) {
        o0[dt] = (floatx4){0.f, 0.f, 0.f, 0.f};
        o1[dt] = (floatx4){0.f, 0.f, 0.f, 0.f};
    }
    float mA = NEG_BIG, lA = 0.f, mB = NEG_BIG, lB = 0.f;

    // staging assignment
    int kkey = tid >> 2, koff = (tid & 3) * 16;
    int vd = tid >> 1, va = tid & 1;  // V: keys 32*va..+31 of row vd

    short8 krH0, krH1, krL0, krL1, vr0, vr1, vr2, vr3;
    unsigned int mwA0, mwA1, mwB0, mwB1;

    {  // prologue: load tile 0
        int kb = kbase;
        const unsigned short* ksrcH = Wht_hi + (size_t)(b * NTOK + kb + kkey) * DHID + koff;
        const unsigned short* ksrcL = Wht_lo + (size_t)(b * NTOK + kb + kkey) * DHID + koff;
        krH0 = *reinterpret_cast<const short8*>(ksrcH);
        krH1 = *reinterpret_cast<const short8*>(ksrcH + 8);
        krL0 = *reinterpret_cast<const short8*>(ksrcL);
        krL1 = *reinterpret_cast<const short8*>(ksrcL + 8);
        const unsigned short* vsrc = WhcT + (size_t)(b * DOUT + vd) * NTOK + kb + va * 32;
        vr0 = *reinterpret_cast<const short8*>(vsrc);
        vr1 = *reinterpret_cast<const short8*>(vsrc + 8);
        vr2 = *reinterpret_cast<const short8*>(vsrc + 16);
        vr3 = *reinterpret_cast<const short8*>(vsrc + 24);
        mwA0 = bits[nA * NWRD + (kb >> 5)];
        mwA1 = bits[nA * NWRD + (kb >> 5) + 1];
        mwB0 = bits[nB * NWRD + (kb >> 5)];
        mwB1 = bits[nB * NWRD + (kb >> 5) + 1];
    }

    for (int it = 0; it < ITERS; ++it) {
        __syncthreads();  // previous tile's compute done
        *reinterpret_cast<short8*>(&Kh_lds[kkey][koff]) = krH0;
        *reinterpret_cast<short8*>(&Kh_lds[kkey][koff + 8]) = krH1;
        *reinterpret_cast<short8*>(&Kl_lds[kkey][koff]) = krL0;
        *reinterpret_cast<short8*>(&Kl_lds[kkey][koff + 8]) = krL1;
        // V permuted slots, regrouped as 4 x b128 (same slot contents as the
        // b64 form, verified: slot(32a+8j+4h+t) = 32a+16(j&1)+8h+4(j>>1)+t)
        {
            int sb = va * 32;
            short8 w00 = __builtin_shufflevector(vr0, vr2, 0, 1, 2, 3, 8, 9, 10, 11);
            short8 w01 = __builtin_shufflevector(vr0, vr2, 4, 5, 6, 7, 12, 13, 14, 15);
            short8 w10 = __builtin_shufflevector(vr1, vr3, 0, 1, 2, 3, 8, 9, 10, 11);
            short8 w11 = __builtin_shufflevector(vr1, vr3, 4, 5, 6, 7, 12, 13, 14, 15);
            *reinterpret_cast<short8*>(&V_lds[vd][sb]) = w00;
            *reinterpret_cast<short8*>(&V_lds[vd][sb + 8]) = w01;
            *reinterpret_cast<short8*>(&V_lds[vd][sb + 16]) = w10;
            *reinterpret_cast<short8*>(&V_lds[vd][sb + 24]) = w11;
        }
        __syncthreads();  // tile visible

        // S^T = K Q^T, hi/lo cross terms, both q-groups share the K fragments
        floatx4 s0[4], s1[4];
        __builtin_amdgcn_s_setprio(1);
#pragma unroll
        for (int kc = 0; kc < 4; ++kc) {
            short8 kh0 = *reinterpret_cast<const short8*>(&Kh_lds[kc * 16 + lc][lg * 8]);
            short8 kh1 = *reinterpret_cast<const short8*>(&Kh_lds[kc * 16 + lc][32 + lg * 8]);
            short8 kl0 = *reinterpret_cast<const short8*>(&Kl_lds[kc * 16 + lc][lg * 8]);
            short8 kl1 = *reinterpret_cast<const short8*>(&Kl_lds[kc * 16 + lc][32 + lg * 8]);
            floatx4 a0 = {0.f, 0.f, 0.f, 0.f};
            a0 = mfma16(kh0, qAh0, a0);
            a0 = mfma16(kh1, qAh1, a0);
            a0 = mfma16(kh0, qAl0, a0);
            a0 = mfma16(kh1, qAl1, a0);
            a0 = mfma16(kl0, qAh0, a0);
            a0 = mfma16(kl1, qAh1, a0);
            s0[kc] = a0;
            floatx4 a1 = {0.f, 0.f, 0.f, 0.f};
            a1 = mfma16(kh0, qBh0, a1);
            a1 = mfma16(kh1, qBh1, a1);
            a1 = mfma16(kh0, qBl0, a1);
            a1 = mfma16(kh1, qBl1, a1);
            a1 = mfma16(kl0, qBh0, a1);
            a1 = mfma16(kl1, qBh1, a1);
            s1[kc] = a1;
        }
        __builtin_amdgcn_s_setprio(0);

        // adjacency mask: key = 16kc+4lg+r -> word kc>>1, bit 16*(kc&1)+4lg+r
#pragma unroll
        for (int kc = 0; kc < 4; ++kc) {
            unsigned int wA = (kc & 2) ? mwA1 : mwA0;
            unsigned int wB = (kc & 2) ? mwB1 : mwB0;
#pragma unroll
            for (int r = 0; r < 4; ++r) {
                int bit = 16 * (kc & 1) + 4 * lg + r;
                if (!((wA >> bit) & 1u)) s0[kc][r] = NEG_BIG;
                if (!((wB >> bit) & 1u)) s1[kc][r] = NEG_BIG;
            }
        }

        // prefetch next tile (global -> reg, hidden under softmax+PV)
        if (it + 1 < ITERS) {
            int kb = kbase + (it + 1) * 64;
            const unsigned short* ksrcH = Wht_hi + (size_t)(b * NTOK + kb + kkey) * DHID + koff;
            const unsigned short* ksrcL = Wht_lo + (size_t)(b * NTOK + kb + kkey) * DHID + koff;
            krH0 = *reinterpret_cast<const short8*>(ksrcH);
            krH1 = *reinterpret_cast<const short8*>(ksrcH + 8);
            krL0 = *reinterpret_cast<const short8*>(ksrcL);
            krL1 = *reinterpret_cast<const short8*>(ksrcL + 8);
            const unsigned short* vsrc = WhcT + (size_t)(b * DOUT + vd) * NTOK + kb + va * 32;
            vr0 = *reinterpret_cast<const short8*>(vsrc);
            vr1 = *reinterpret_cast<const short8*>(vsrc + 8);
            vr2 = *reinterpret_cast<const short8*>(vsrc + 16);
            vr3 = *reinterpret_cast<const short8*>(vsrc + 24);
            mwA0 = bits[nA * NWRD + (kb >> 5)];
            mwA1 = bits[nA * NWRD + (kb >> 5) + 1];
            mwB0 = bits[nB * NWRD + (kb >> 5)];
            mwB1 = bits[nB * NWRD + (kb >> 5) + 1];
        }

        // online softmax, group A (q = q0+lc)
        float scA, scB;
        {
            float vm = s0[0][0];
#pragma unroll
            for (int kc = 0; kc < 4; ++kc)
#pragma unroll
                for (int r = 0; r < 4; ++r) vm = fmaxf(vm, s0[kc][r]);
            vm = fmaxf(vm, __shfl_xor(vm, 16));
            vm = fmaxf(vm, __shfl_xor(vm, 32));
            float mn = fmaxf(mA, vm);
            scA = __expf(mA - mn);
            mA = mn;
            float rs = 0.f;
#pragma unroll
            for (int kc = 0; kc < 4; ++kc)
#pragma unroll
                for (int r = 0; r < 4; ++r) {
                    float p = __expf(s0[kc][r] - mn);
                    s0[kc][r] = p;
                    rs += p;
                }
            rs += __shfl_xor(rs, 16);
            rs += __shfl_xor(rs, 32);
            lA = lA * scA + rs;
        }
        // group B (q = q0+16+lc)
        {
            float vm = s1[0][0];
#pragma unroll
            for (int kc = 0; kc < 4; ++kc)
#pragma unroll
                for (int r = 0; r < 4; ++r) vm = fmaxf(vm, s1[kc][r]);
            vm = fmaxf(vm, __shfl_xor(vm, 16));
            vm = fmaxf(vm, __shfl_xor(vm, 32));
            float mn = fmaxf(mB, vm);
            scB = __expf(mB - mn);
            mB = mn;
            float rs = 0.f;
#pragma unroll
            for (int kc = 0; kc < 4; ++kc)
#pragma unroll
                for (int r = 0; r < 4; ++r) {
                    float p = __expf(s1[kc][r] - mn);
                    s1[kc][r] = p;
                    rs += p;
                }
            rs += __shfl_xor(rs, 16);
            rs += __shfl_xor(rs, 32);
            lB = lB * scB + rs;
        }

        // rescale o (rows are q=16qg+4lg+r; sc lives at q=16qg+lc)
        {
            float sc4[4];
#pragma unroll
            for (int r = 0; r < 4; ++r) sc4[r] = __shfl(scA, (lane & 48) + 4 * lg + r);
#pragma unroll
            for (int dt = 0; dt < 8; ++dt)
#pragma unroll
                for (int r = 0; r < 4; ++r) o0[dt][r] *= sc4[r];
#pragma unroll
            for (int r = 0; r < 4; ++r) sc4[r] = __shfl(scB, (lane & 48) + 4 * lg + r);
#pragma unroll
            for (int dt = 0; dt < 8; ++dt)
#pragma unroll
                for (int r = 0; r < 4; ++r) o1[dt][r] *= sc4[r];
        }

        // pack PV A-operands in-register
        unsigned int pw[8];
        pw[0] = pk2(s0[0][0], s0[0][1]); pw[1] = pk2(s0[0][2], s0[0][3]);
        pw[2] = pk2(s0[1][0], s0[1][1]); pw[3] = pk2(s0[1][2], s0[1][3]);
        pw[4] = pk2(s0[2][0], s0[2][1]); pw[5] = pk2(s0[2][2], s0[2][3]);
        pw[6] = pk2(s0[3][0], s0[3][1]); pw[7] = pk2(s0[3][2], s0[3][3]);
        short8 paA0 = __builtin_bit_cast(short8, *reinterpret_cast<uint4*>(&pw[0]));
        short8 paA1 = __builtin_bit_cast(short8, *reinterpret_cast<uint4*>(&pw[4]));
        pw[0] = pk2(s1[0][0], s1[0][1]); pw[1] = pk2(s1[0][2], s1[0][3]);
        pw[2] = pk2(s1[1][0], s1[1][1]); pw[3] = pk2(s1[1][2], s1[1][3]);
        pw[4] = pk2(s1[2][0], s1[2][1]); pw[5] = pk2(s1[2][2], s1[2][3]);
        pw[6] = pk2(s1[3][0], s1[3][1]); pw[7] = pk2(s1[3][2], s1[3][3]);
        short8 paB0 = __builtin_bit_cast(short8, *reinterpret_cast<uint4*>(&pw[0]));
        short8 paB1 = __builtin_bit_cast(short8, *reinterpret_cast<uint4*>(&pw[4]));

        // O += P V  (B col = lc = d, k = permuted slots; vf shared by both qg)
        __builtin_amdgcn_s_setprio(1);
#pragma unroll
        for (int dt = 0; dt < 8; ++dt) {
            short8 vf0 = *reinterpret_cast<const short8*>(&V_lds[dt * 16 + lc][lg * 8]);
            o0[dt] = mfma16(paA0, vf0, o0[dt]);
            o1[dt] = mfma16(paB0, vf0, o1[dt]);
        }
#pragma unroll
        for (int dt = 0; dt < 8; ++dt) {
            short8 vf1 = *reinterpret_cast<const short8*>(&V_lds[dt * 16 + lc][32 + lg * 8]);
            o0[dt] = mfma16(paA1, vf1, o0[dt]);
            o1[dt] = mfma16(paB1, vf1, o1[dt]);
        }
        __builtin_amdgcn_s_setprio(0);
    }

    // epilogue: o rows are q = q0+16qg+4lg+r; softmax state lives at q-group's lc
    {
        float m4[4], l4[4];
#pragma unroll
        for (int r = 0; r < 4; ++r) {
            int src = (lane & 48) + 4 * lg + r;
            m4[r] = __shfl(mA, src);
            l4[r] = __shfl(lA, src);
        }
#pragma unroll
        for (int r = 0; r < 4; ++r) {
            size_t row = (size_t)(split * BATCH + b) * NTOK + q0 + 4 * lg + r;
            unsigned short* prow = po + row * DOUT;
#pragma unroll
            for (int dt = 0; dt < 8; ++dt) prow[dt * 16 + lc] = f2bf(o0[dt][r]);
            if (lc == 0) {
                pm[row] = m4[r];
                pl[row] = l4[r];
            }
        }
#pragma unroll
        for (int r = 0; r < 4; ++r) {
            int src = (lane & 48) + 4 * lg + r;
            m4[r] = __shfl(mB, src);
            l4[r] = __shfl(lB, src);
        }
#pragma unroll
        for (int r = 0; r < 4; ++r) {
            size_t row = (size_t)(split * BATCH + b) * NTOK + q0 + 16 + 4 * lg + r;
            unsigned short* prow = po + row * DOUT;
#pragma unroll
            for (int dt = 0; dt < 8; ++dt) prow[dt * 16 + lc] = f2bf(o1[dt][r]);
            if (lc == 0) {
                pm[row] = m4[r];
                pl[row] = l4[r];
            }
        }
    }
}

// ---------------------------------------------------------------- merge
__global__ __launch_bounds__(256) void merge_kernel(const unsigned short* __restrict__ po,
                                                    const float* __restrict__ pm,
                                                    const float* __restrict__ pl,
                                                    float* __restrict__ out) {
    int idx = blockIdx.x * 256 + threadIdx.x;
    int d = idx & (DOUT - 1);
    size_t bn = (size_t)(idx >> 7);
    const size_t BN = (size_t)BATCH * NTOK;

    float ms[SPLIT];
#pragma unroll
    for (int s = 0; s < SPLIT; ++s) ms[s] = pm[s * BN + bn];
    float M = ms[0];
#pragma unroll
    for (int s = 1; s < SPLIT; ++s) M = fmaxf(M, ms[s]);
    float L = 0.f, acc = 0.f;
#pragma unroll
    for (int s = 0; s < SPLIT; ++s) {
        float e = __expf(ms[s] - M);
        L += pl[s * BN + bn] * e;
        acc += bf2f(po[(s * BN + bn) * DOUT + d]) * e;
    }
    out[idx] = acc / L;
}

// ---------------------------------------------------------------- launch
extern "C" void kernel_launch(void* const* d_in, const int* in_sizes, int n_in,
                              void* d_out, int out_size, void* d_ws, size_t ws_size,
                              hipStream_t stream) {
    const float* h   = (const float*)d_in[0];
    const int*   adj = (const int*)d_in[1];
    const float* Ws  = (const float*)d_in[2];
    const float* Wt  = (const float*)d_in[3];
    const float* Wc  = (const float*)d_in[4];
    float* out = (float*)d_out;

    // workspace layout (~31 MiB)
    size_t nq = (size_t)BATCH * NTOK * DHID;
    unsigned short* Whs_hi = (unsigned short*)d_ws;                                // 2 MiB
    unsigned short* Whs_lo = Whs_hi + nq;                                          // 2 MiB
    unsigned short* Wht_hi = Whs_lo + nq;                                          // 2 MiB
    unsigned short* Wht_lo = Wht_hi + nq;                                          // 2 MiB
    unsigned short* WhcT   = Wht_lo + nq;                                          // 4 MiB
    unsigned int*   bits   = (unsigned int*)(WhcT + (size_t)BATCH * DOUT * NTOK);  // 2 MiB
    unsigned short* WT_hi  = (unsigned short*)(bits + (size_t)NTOK * NWRD);        // 64 KiB
    unsigned short* WT_lo  = WT_hi + 256 * DIN;                                    // 32 KiB
    unsigned short* po     = WT_lo + 128 * DIN;                                    // 16 MiB
    float*          pm     = (float*)(po + (size_t)SPLIT * BATCH * NTOK * DOUT);   // 256 KiB
    float*          pl     = pm + (size_t)SPLIT * BATCH * NTOK;                    // 256 KiB

    pack_adj_kernel<<<dim3(NTOK * NWRD / 256), dim3(256), 0, stream>>>(adj, bits);
    conv_w_kernel<<<dim3(128), dim3(256), 0, stream>>>(Ws, Wt, Wc, WT_hi, WT_lo);
    prep_kernel<<<dim3(NTOK / 16, BATCH), dim3(256), 0, stream>>>(
        h, WT_hi, WT_lo, Whs_hi, Whs_lo, Wht_hi, Wht_lo, WhcT);
    attn_kernel<<<dim3(NTOK / 128, BATCH, SPLIT), dim3(256), 0, stream>>>(
        Whs_hi, Whs_lo, Wht_hi, Wht_lo, WhcT, bits, po, pm, pl);
    merge_kernel<<<dim3(BATCH * NTOK * DOUT / 256), dim3(256), 0, stream>>>(po, pm, pl, out);
}